// Round 10
// baseline (154.183 us; speedup 1.0000x reference)
//
#include <hip/hip_runtime.h>
#include <math.h>

// Bucketed rank/cumsum (round 10): round-9 (green) structure; only change is
// eliminating k_main's two random gathers (yt0[2*idx+1], yp0[idx]):
//   - event bit packed into sidx bit 31 (idx < 2^18 << 2^31),
//   - xbeta recovered as log(e) from the carried e=exp(xbeta):
//       contrib = ev * logf(denom / e)   == ev*(log denom - xbeta) to ~1e-6.
//   - yt0 read as coalesced float2 in k_hist/k_scatter.
//   key = float bits of time (positive floats order monotonically).
//   bucket = key >> 12 -> 2^19 buckets covers every positive float.
//   k_hist: R=4 replicas (16-way dense-octave contention); seq[i] = atomicAdd
//   return = slot within (r,bucket). Suffix scans over buckets give
//   (count above, exp-sum above); within-bucket order resolved exactly in
//   k_main (order-invariant, replay-deterministic).
// Tie-break (key desc, idx asc) matches jax.lax.top_k stability.

#define BSHIFT 12
#define NBUCK (1 << 19)           // 524288
#define SCAN_BLK 1024
#define NPART (NBUCK / SCAN_BLK)  // 512
#define RMAX 4

__global__ void k_hist(const float2* __restrict__ yt0, const float* __restrict__ yp0,
                       int n, int rmask,
                       unsigned* __restrict__ count, float* __restrict__ expsum,
                       unsigned* __restrict__ seq) {
  int i = blockIdx.x * blockDim.x + threadIdx.x;
  if (i >= n) return;
  int r = blockIdx.x & rmask;
  unsigned key = __float_as_uint(yt0[i].x);
  unsigned b = key >> BSHIFT;
  seq[i] = atomicAdd(&count[(size_t)r * NBUCK + b], 1u);
  atomicAdd(&expsum[(size_t)r * NBUCK + b], expf(yp0[i]));
}

// Fold replicas (countTot/expTot/offArr) AND produce per-part suffix totals.
__global__ void k_scan_reduce(const unsigned* __restrict__ count, const float* __restrict__ expsum,
                              int nrep,
                              unsigned* __restrict__ countTot, float* __restrict__ expTot,
                              unsigned* __restrict__ offArr,
                              unsigned* __restrict__ cntPart, float* __restrict__ expPart) {
  __shared__ unsigned sc[SCAN_BLK];
  __shared__ float sf[SCAN_BLK];
  int t = threadIdx.x, g = blockIdx.x;
  int b = NBUCK - 1 - (g * SCAN_BLK + t);  // reversed order -> suffix scan
  unsigned tot = 0;
  float ftot = 0.f;
  for (int r = 0; r < nrep; ++r) {
    offArr[(size_t)r * NBUCK + b] = tot;
    tot += count[(size_t)r * NBUCK + b];
    ftot += expsum[(size_t)r * NBUCK + b];
  }
  countTot[b] = tot;
  expTot[b] = ftot;
  sc[t] = tot;
  sf[t] = ftot;
  __syncthreads();
  for (int s = SCAN_BLK / 2; s > 0; s >>= 1) {
    if (t < s) { sc[t] += sc[t + s]; sf[t] += sf[t + s]; }
    __syncthreads();
  }
  if (t == 0) { cntPart[g] = sc[0]; expPart[g] = sf[0]; }
}

// Phase 1: per-block reduce of part totals for parts BEFORE this one (reversed
// order). Phase 2: intra-part inclusive scan. NPART (512) <= SCAN_BLK.
__global__ void k_scan_final(const unsigned* __restrict__ count, const float* __restrict__ expsum,
                             const unsigned* __restrict__ cntPart, const float* __restrict__ expPart,
                             unsigned* __restrict__ sfxCnt, float* __restrict__ sfxExp) {
  __shared__ unsigned sc[SCAN_BLK];
  __shared__ float sf[SCAN_BLK];
  int t = threadIdx.x, g = blockIdx.x;
  sc[t] = (t < g) ? cntPart[t] : 0u;
  sf[t] = (t < g) ? expPart[t] : 0.f;
  __syncthreads();
  for (int s = SCAN_BLK / 2; s > 0; s >>= 1) {
    if (t < s) { sc[t] += sc[t + s]; sf[t] += sf[t + s]; }
    __syncthreads();
  }
  unsigned basC = sc[0];
  float basF = sf[0];
  __syncthreads();
  int b = NBUCK - 1 - (g * SCAN_BLK + t);
  sc[t] = count[b];
  sf[t] = expsum[b];
  __syncthreads();
  for (int off = 1; off < SCAN_BLK; off <<= 1) {
    unsigned c = 0; float f = 0.f;
    if (t >= off) { c = sc[t - off]; f = sf[t - off]; }
    __syncthreads();
    sc[t] += c; sf[t] += f;
    __syncthreads();
  }
  sfxCnt[b] = sc[t] + basC;  // inclusive suffix: sum over buckets >= b
  sfxExp[b] = sf[t] + basF;
}

__global__ void k_scatter(const float2* __restrict__ yt0, const float* __restrict__ yp0, int n,
                          int rmask,
                          const unsigned* __restrict__ countTot, const unsigned* __restrict__ sfxCnt,
                          const unsigned* __restrict__ offArr, const unsigned* __restrict__ seq,
                          uint2* __restrict__ skey2, unsigned* __restrict__ sidx) {
  int i = blockIdx.x * blockDim.x + threadIdx.x;
  if (i >= n) return;
  int r = blockIdx.x & rmask;  // same mapping as k_hist (same grid/block config)
  float2 te = yt0[i];
  unsigned key = __float_as_uint(te.x);
  unsigned ev = (te.y != 0.f) ? 0x80000000u : 0u;
  unsigned b = key >> BSHIFT;
  unsigned start = sfxCnt[b] - countTot[b];  // # elements in strictly-higher buckets
  unsigned pos = start + offArr[(size_t)r * NBUCK + b] + seq[i];
  uint2 v; v.x = key; v.y = __float_as_uint(expf(yp0[i]));
  skey2[pos] = v;
  sidx[pos] = (unsigned)i | ev;   // event bit in bit 31; idx in low 31 bits
}

__global__ void k_main(const float* __restrict__ yp1, const int* __restrict__ Hj,
                       int n, int m,
                       const unsigned* __restrict__ countTot, const float* __restrict__ expTot,
                       const unsigned* __restrict__ sfxCnt, const float* __restrict__ sfxExp,
                       const uint2* __restrict__ skey2, const unsigned* __restrict__ sidx,
                       float* __restrict__ xh, double* __restrict__ accum) {
  int p = blockIdx.x * blockDim.x + threadIdx.x;
  double contrib = 0.0;
  if (p < n) {
    uint2 kv = skey2[p];
    unsigned key = kv.x;
    float e = __uint_as_float(kv.y);
    unsigned sidv = sidx[p];
    unsigned idx = sidv & 0x7FFFFFFFu;
    bool ev = (sidv >> 31) != 0u;
    unsigned b = key >> BSHIFT;
    unsigned end = sfxCnt[b];
    unsigned start = end - countTot[b];
    // defensive clamps: corrupt bounds can never cause runaway loops
    if (end > (unsigned)n) end = (unsigned)n;
    if (start > end) start = end;
    float wsum = 0.f;
    unsigned wcnt = 0;
    unsigned q = start;
    // 8x unrolled batched loads: 8 independent uint2 loads per iteration (MLP);
    // sidx loaded only on exact-key tie (rare).
    while (q + 8 <= end) {
      uint2 v[8];
      #pragma unroll
      for (int k = 0; k < 8; ++k) v[k] = skey2[q + k];
      #pragma unroll
      for (int k = 0; k < 8; ++k) {
        if (v[k].x > key) { wsum += __uint_as_float(v[k].y); wcnt++; }
        else if (v[k].x == key && (sidx[q + k] & 0x7FFFFFFFu) < idx) {
          wsum += __uint_as_float(v[k].y); wcnt++;
        }
      }
      q += 8;
    }
    for (; q < end; ++q) {
      uint2 v = skey2[q];
      if (v.x > key) { wsum += __uint_as_float(v.y); wcnt++; }
      else if (v.x == key && (sidx[q] & 0x7FFFFFFFu) < idx) {
        wsum += __uint_as_float(v.y); wcnt++;
      }
    }
    // denom = exp-sum of all elements strictly before p in descending-time order, + self
    float denom = (sfxExp[b] - expTot[b]) + wsum + e;
    int rank = (int)(start + wcnt);
    // lossA element: ev*(log(denom) - xbeta) == ev*log(denom/e) since e=exp(xbeta)
    contrib = ev ? (double)logf(denom / e) : 0.0;
    // scatter y_pred1 to ordinal anchor slots whose sorted position == rank
    int lo = 0, hi = m;
    while (lo < hi) { int mid = (lo + hi) >> 1; if (Hj[mid] < rank) lo = mid + 1; else hi = mid; }
    if (lo < m && Hj[lo] == rank) {
      float xb1 = yp1[idx];
      for (int j = lo; j < m && Hj[j] == rank; ++j) xh[j] = xb1;
    }
  }
  __shared__ double red[256];
  int t = threadIdx.x;
  red[t] = contrib;
  __syncthreads();
  for (int s = 128; s > 0; s >>= 1) {
    if (t < s) red[t] += red[t + s];
    __syncthreads();
  }
  if (t == 0) atomicAdd(accum, red[0]);
}

// cost2 = M(M+1)/2 - sum_j exp(xh_j) * S_j,  S_j = inclusive suffix sum of exp(-xh).
// Wave-shuffle suffix scan: 8 elem/thread, 6 shfl steps/wave, 16 wave totals via
// LDS, 2 syncs per 8192-element pass.
__global__ void k_final(const float* __restrict__ xh, int m,
                        const double* __restrict__ accum, const float* __restrict__ log_vars,
                        int n, float* __restrict__ out) {
  __shared__ float wtots[16];
  __shared__ double dred[1024];
  int t = threadIdx.x;
  int lane = t & 63;
  int w = t >> 6;
  double acc = 0.0;
  float carry = 0.f;
  int passes = (m + 8191) / 8192;
  for (int pss = passes - 1; pss >= 0; --pss) {
    int base = pss * 8192 + t * 8;
    float x[8], eb[8];
    float c = 0.f;
    #pragma unroll
    for (int k = 0; k < 8; ++k) {
      int j = base + k;
      x[k] = (j < m) ? xh[j] : 0.f;
      eb[k] = (j < m) ? expf(-x[k]) : 0.f;
      c += eb[k];
    }
    // inclusive suffix scan of per-thread chunk sums within the wave
    float s = c;
    #pragma unroll
    for (int d = 1; d < 64; d <<= 1) {
      float o = __shfl_down(s, d, 64);
      if (lane + d < 64) s += o;
    }
    float wtot = __shfl(s, 0, 64);   // wave total (lane 0 holds full suffix)
    if (lane == 0) wtots[w] = wtot;
    __syncthreads();
    float after = 0.f;
    #pragma unroll
    for (int w2 = 0; w2 < 16; ++w2) if (w2 > w) after += wtots[w2];
    float ptot = 0.f;
    #pragma unroll
    for (int w2 = 0; w2 < 16; ++w2) ptot += wtots[w2];
    float S = (s - c) + after + carry;
    #pragma unroll
    for (int k = 7; k >= 0; --k) {
      int j = base + k;
      S += eb[k];
      if (j < m) acc += (double)(expf(x[k]) * S);
    }
    __syncthreads();   // protect wtots before next pass overwrites
    carry += ptot;
  }
  dred[t] = acc;
  __syncthreads();
  for (int s2 = 512; s2 > 0; s2 >>= 1) {
    if (t < s2) dred[t] += dred[t + s2];
    __syncthreads();
  }
  if (t == 0) {
    double T = (double)m * (double)(m + 1) * 0.5;
    double cost2 = T - dred[0];
    float lv0 = log_vars[0], lv1 = log_vars[1];
    float prec1 = fminf(expf(-lv1), 1.0f);  // clip(exp(-lv1),0,1)
    double loss = *accum + (double)n * (double)lv0 + (double)prec1 * cost2 + (double)lv1;
    out[0] = (float)loss;
  }
}

extern "C" void kernel_launch(void* const* d_in, const int* in_sizes, int n_in,
                              void* d_out, int out_size, void* d_ws, size_t ws_size,
                              hipStream_t stream) {
  const float2* yt0 = (const float2*)d_in[0];
  const float*  yp0 = (const float*)d_in[2];
  const float*  yp1 = (const float*)d_in[3];
  const int*    Hj  = (const int*)d_in[4];
  const float*  lv  = (const float*)d_in[5];
  int n = in_sizes[0] / 2;  // y_true0 is [N,2]
  int m = in_sizes[4];

  // Replica count: 4 if workspace fits (~38 MB at NBUCK=2^19), else 1.
  int nrep = RMAX;
  {
    size_t need = (size_t)nrep * NBUCK * 4 * 3   // count, expsum, offArr
                + (size_t)NBUCK * 4 * 4          // countTot, expTot, sfxCnt, sfxExp
                + (size_t)NPART * 4 * 2
                + (size_t)n * 4 * 4              // seq, skey2 (8B), sidx
                + (size_t)m * 4 + 256;
    if (ws_size < need) nrep = 1;
  }
  int rmask = nrep - 1;

  char* ws = (char*)d_ws;
  size_t off = 0;
  unsigned* count  = (unsigned*)(ws + off); off += (size_t)nrep * NBUCK * 4;
  float*    expsum = (float*)(ws + off);    off += (size_t)nrep * NBUCK * 4;
  double*   accum  = (double*)(ws + off);   off += 16;
  size_t zbytes = off;  // everything above must start zeroed
  unsigned* offArr  = (unsigned*)(ws + off); off += (size_t)nrep * NBUCK * 4;
  unsigned* countTot= (unsigned*)(ws + off); off += (size_t)NBUCK * 4;
  float*    expTot  = (float*)(ws + off);    off += (size_t)NBUCK * 4;
  unsigned* cntPart = (unsigned*)(ws + off); off += (size_t)NPART * 4;
  float*    expPart = (float*)(ws + off);    off += (size_t)NPART * 4;
  unsigned* sfxCnt  = (unsigned*)(ws + off); off += (size_t)NBUCK * 4;
  float*    sfxExp  = (float*)(ws + off);    off += (size_t)NBUCK * 4;
  unsigned* seq     = (unsigned*)(ws + off); off += (size_t)n * 4;
  uint2*    skey2   = (uint2*)(ws + off);    off += (size_t)n * 8;   // 8-aligned
  unsigned* sidx    = (unsigned*)(ws + off); off += (size_t)n * 4;
  float*    xh      = (float*)(ws + off);    off += (size_t)m * 4;

  hipMemsetAsync(d_ws, 0, zbytes, stream);

  int blk = 256;
  int g_n = (n + blk - 1) / blk;
  k_hist<<<g_n, blk, 0, stream>>>(yt0, yp0, n, rmask, count, expsum, seq);
  k_scan_reduce<<<NPART, SCAN_BLK, 0, stream>>>(count, expsum, nrep,
                                                countTot, expTot, offArr, cntPart, expPart);
  k_scan_final<<<NPART, SCAN_BLK, 0, stream>>>(countTot, expTot, cntPart, expPart, sfxCnt, sfxExp);
  k_scatter<<<g_n, blk, 0, stream>>>(yt0, yp0, n, rmask, countTot, sfxCnt, offArr, seq,
                                     skey2, sidx);
  k_main<<<g_n, blk, 0, stream>>>(yp1, Hj, n, m, countTot, expTot, sfxCnt, sfxExp,
                                  skey2, sidx, xh, accum);
  k_final<<<1, 1024, 0, stream>>>(xh, m, accum, lv, n, (float*)d_out);
}

// Round 11
// 139.483 us; speedup vs baseline: 1.1054x; 1.1054x over previous
//
#include <hip/hip_runtime.h>
#include <math.h>

// Bucketed rank/cumsum (round 11): round-10 (green) structure with the float
// expsum atomic pipeline removed. Cross-bucket exp term now comes from an
// exclusive prefix sum over the scattered se array (positions < bucket start
// == all strictly-higher-time elements), computed by k_scan_se (in-block
// inclusive scans + block totals) + a 256-entry LDS scan in k_main's prologue.
//   k_hist: int count atomic ONLY (was int+float at same contention);
//   scans stream count replicas only (half the bytes).
//   key = float bits of time (positive floats order monotonically).
//   bucket = key >> 12 -> 2^19 buckets covers every positive float.
//   R=4 replicas; seq[i] = atomicAdd return = slot within (r,bucket).
//   Within-bucket order resolved exactly in k_main (order-invariant).
// Tie-break (key desc, idx asc) matches jax.lax.top_k stability.

#define BSHIFT 12
#define NBUCK (1 << 19)           // 524288
#define SCAN_BLK 1024
#define NPART (NBUCK / SCAN_BLK)  // 512
#define RMAX 4
#define SEBLK 1024                // k_scan_se block width

__global__ void k_hist(const float2* __restrict__ yt0, int n, int rmask,
                       unsigned* __restrict__ count, unsigned* __restrict__ seq) {
  int i = blockIdx.x * blockDim.x + threadIdx.x;
  if (i >= n) return;
  int r = blockIdx.x & rmask;
  unsigned key = __float_as_uint(yt0[i].x);
  unsigned b = key >> BSHIFT;
  seq[i] = atomicAdd(&count[(size_t)r * NBUCK + b], 1u);
}

// Fold replicas (countTot/offArr) AND produce per-part suffix totals.
__global__ void k_scan_reduce(const unsigned* __restrict__ count, int nrep,
                              unsigned* __restrict__ countTot,
                              unsigned* __restrict__ offArr,
                              unsigned* __restrict__ cntPart) {
  __shared__ unsigned sc[SCAN_BLK];
  int t = threadIdx.x, g = blockIdx.x;
  int b = NBUCK - 1 - (g * SCAN_BLK + t);  // reversed order -> suffix scan
  unsigned tot = 0;
  for (int r = 0; r < nrep; ++r) {
    offArr[(size_t)r * NBUCK + b] = tot;
    tot += count[(size_t)r * NBUCK + b];
  }
  countTot[b] = tot;
  sc[t] = tot;
  __syncthreads();
  for (int s = SCAN_BLK / 2; s > 0; s >>= 1) {
    if (t < s) sc[t] += sc[t + s];
    __syncthreads();
  }
  if (t == 0) cntPart[g] = sc[0];
}

// Phase 1: per-block reduce of part totals for parts BEFORE this one (reversed
// order). Phase 2: intra-part inclusive scan. NPART (512) <= SCAN_BLK.
__global__ void k_scan_final(const unsigned* __restrict__ count,
                             const unsigned* __restrict__ cntPart,
                             unsigned* __restrict__ sfxCnt) {
  __shared__ unsigned sc[SCAN_BLK];
  int t = threadIdx.x, g = blockIdx.x;
  sc[t] = (t < g) ? cntPart[t] : 0u;
  __syncthreads();
  for (int s = SCAN_BLK / 2; s > 0; s >>= 1) {
    if (t < s) sc[t] += sc[t + s];
    __syncthreads();
  }
  unsigned basC = sc[0];
  __syncthreads();
  int b = NBUCK - 1 - (g * SCAN_BLK + t);
  sc[t] = count[b];
  __syncthreads();
  for (int off = 1; off < SCAN_BLK; off <<= 1) {
    unsigned c = 0;
    if (t >= off) c = sc[t - off];
    __syncthreads();
    sc[t] += c;
    __syncthreads();
  }
  sfxCnt[b] = sc[t] + basC;  // inclusive suffix: sum over buckets >= b
}

__global__ void k_scatter(const float2* __restrict__ yt0, const float* __restrict__ yp0, int n,
                          int rmask,
                          const unsigned* __restrict__ countTot, const unsigned* __restrict__ sfxCnt,
                          const unsigned* __restrict__ offArr, const unsigned* __restrict__ seq,
                          uint2* __restrict__ skey2, unsigned* __restrict__ sidx) {
  int i = blockIdx.x * blockDim.x + threadIdx.x;
  if (i >= n) return;
  int r = blockIdx.x & rmask;  // same mapping as k_hist (same grid/block config)
  float2 te = yt0[i];
  unsigned key = __float_as_uint(te.x);
  unsigned ev = (te.y != 0.f) ? 0x80000000u : 0u;
  unsigned b = key >> BSHIFT;
  unsigned start = sfxCnt[b] - countTot[b];  // # elements in strictly-higher buckets
  unsigned pos = start + offArr[(size_t)r * NBUCK + b] + seq[i];
  uint2 v; v.x = key; v.y = __float_as_uint(expf(yp0[i]));
  skey2[pos] = v;
  sidx[pos] = (unsigned)i | ev;   // event bit in bit 31; idx in low 31 bits
}

// In-block inclusive prefix scan of se (scattered order) + block totals.
// Exclusive global prefix at position p = blockBase(p>>10) + inblock(p-1).
__global__ void k_scan_se(const uint2* __restrict__ skey2, int n,
                          float* __restrict__ preS, float* __restrict__ blockTot) {
  __shared__ float sf[SEBLK];
  int t = threadIdx.x;
  int p = blockIdx.x * SEBLK + t;
  float v = (p < n) ? __uint_as_float(skey2[p].y) : 0.f;
  sf[t] = v;
  __syncthreads();
  for (int off = 1; off < SEBLK; off <<= 1) {
    float a = 0.f;
    if (t >= off) a = sf[t - off];
    __syncthreads();
    sf[t] += a;
    __syncthreads();
  }
  if (p < n) preS[p] = sf[t];                    // inclusive within block
  if (t == SEBLK - 1) blockTot[blockIdx.x] = sf[t];
}

__global__ void k_main(const float* __restrict__ yp1, const int* __restrict__ Hj,
                       int n, int m, int seParts,
                       const unsigned* __restrict__ countTot,
                       const unsigned* __restrict__ sfxCnt,
                       const uint2* __restrict__ skey2, const unsigned* __restrict__ sidx,
                       const float* __restrict__ preS, const float* __restrict__ blockTot,
                       float* __restrict__ xh, double* __restrict__ accum) {
  __shared__ float pb[256];   // inclusive prefix of blockTot (seParts <= 256)
  __shared__ double red[256];
  int t = threadIdx.x;
  pb[t] = (t < seParts) ? blockTot[t] : 0.f;
  __syncthreads();
  for (int off = 1; off < 256; off <<= 1) {
    float a = 0.f;
    if (t >= off) a = pb[t - off];
    __syncthreads();
    pb[t] += a;
    __syncthreads();
  }

  int p = blockIdx.x * blockDim.x + t;
  double contrib = 0.0;
  if (p < n) {
    uint2 kv = skey2[p];
    unsigned key = kv.x;
    float e = __uint_as_float(kv.y);
    unsigned sidv = sidx[p];
    unsigned idx = sidv & 0x7FFFFFFFu;
    bool ev = (sidv >> 31) != 0u;
    unsigned b = key >> BSHIFT;
    unsigned end = sfxCnt[b];
    unsigned start = end - countTot[b];
    // defensive clamps: corrupt bounds can never cause runaway loops
    if (end > (unsigned)n) end = (unsigned)n;
    if (start > end) start = end;
    float wsum = 0.f;
    unsigned wcnt = 0;
    unsigned q = start;
    // 8x unrolled batched loads: 8 independent uint2 loads per iteration (MLP);
    // sidx loaded only on exact-key tie (rare).
    while (q + 8 <= end) {
      uint2 v[8];
      #pragma unroll
      for (int k = 0; k < 8; ++k) v[k] = skey2[q + k];
      #pragma unroll
      for (int k = 0; k < 8; ++k) {
        if (v[k].x > key) { wsum += __uint_as_float(v[k].y); wcnt++; }
        else if (v[k].x == key && (sidx[q + k] & 0x7FFFFFFFu) < idx) {
          wsum += __uint_as_float(v[k].y); wcnt++;
        }
      }
      q += 8;
    }
    for (; q < end; ++q) {
      uint2 v = skey2[q];
      if (v.x > key) { wsum += __uint_as_float(v.y); wcnt++; }
      else if (v.x == key && (sidx[q] & 0x7FFFFFFFu) < idx) {
        wsum += __uint_as_float(v.y); wcnt++;
      }
    }
    // cross-bucket exp term: exclusive prefix of se at 'start'
    unsigned sb = start >> 10;
    float cross = ((sb > 0) ? pb[sb - 1] : 0.f)
                + ((start & 1023u) ? preS[start - 1] : 0.f);
    float denom = cross + wsum + e;
    int rank = (int)(start + wcnt);
    // lossA element: ev*(log(denom) - xbeta) == ev*log(denom/e) since e=exp(xbeta)
    contrib = ev ? (double)logf(denom / e) : 0.0;
    // scatter y_pred1 to ordinal anchor slots whose sorted position == rank
    int lo = 0, hi = m;
    while (lo < hi) { int mid = (lo + hi) >> 1; if (Hj[mid] < rank) lo = mid + 1; else hi = mid; }
    if (lo < m && Hj[lo] == rank) {
      float xb1 = yp1[idx];
      for (int j = lo; j < m && Hj[j] == rank; ++j) xh[j] = xb1;
    }
  }
  red[t] = contrib;
  __syncthreads();
  for (int s = 128; s > 0; s >>= 1) {
    if (t < s) red[t] += red[t + s];
    __syncthreads();
  }
  if (t == 0) atomicAdd(accum, red[0]);
}

// cost2 = M(M+1)/2 - sum_j exp(xh_j) * S_j,  S_j = inclusive suffix sum of exp(-xh).
// Wave-shuffle suffix scan: 8 elem/thread, 6 shfl steps/wave, 16 wave totals via
// LDS, 2 syncs per 8192-element pass.
__global__ void k_final(const float* __restrict__ xh, int m,
                        const double* __restrict__ accum, const float* __restrict__ log_vars,
                        int n, float* __restrict__ out) {
  __shared__ float wtots[16];
  __shared__ double dred[1024];
  int t = threadIdx.x;
  int lane = t & 63;
  int w = t >> 6;
  double acc = 0.0;
  float carry = 0.f;
  int passes = (m + 8191) / 8192;
  for (int pss = passes - 1; pss >= 0; --pss) {
    int base = pss * 8192 + t * 8;
    float x[8], eb[8];
    float c = 0.f;
    #pragma unroll
    for (int k = 0; k < 8; ++k) {
      int j = base + k;
      x[k] = (j < m) ? xh[j] : 0.f;
      eb[k] = (j < m) ? expf(-x[k]) : 0.f;
      c += eb[k];
    }
    float s = c;
    #pragma unroll
    for (int d = 1; d < 64; d <<= 1) {
      float o = __shfl_down(s, d, 64);
      if (lane + d < 64) s += o;
    }
    float wtot = __shfl(s, 0, 64);   // wave total (lane 0 holds full suffix)
    if (lane == 0) wtots[w] = wtot;
    __syncthreads();
    float after = 0.f;
    #pragma unroll
    for (int w2 = 0; w2 < 16; ++w2) if (w2 > w) after += wtots[w2];
    float ptot = 0.f;
    #pragma unroll
    for (int w2 = 0; w2 < 16; ++w2) ptot += wtots[w2];
    float S = (s - c) + after + carry;
    #pragma unroll
    for (int k = 7; k >= 0; --k) {
      int j = base + k;
      S += eb[k];
      if (j < m) acc += (double)(expf(x[k]) * S);
    }
    __syncthreads();   // protect wtots before next pass overwrites
    carry += ptot;
  }
  dred[t] = acc;
  __syncthreads();
  for (int s2 = 512; s2 > 0; s2 >>= 1) {
    if (t < s2) dred[t] += dred[t + s2];
    __syncthreads();
  }
  if (t == 0) {
    double T = (double)m * (double)(m + 1) * 0.5;
    double cost2 = T - dred[0];
    float lv0 = log_vars[0], lv1 = log_vars[1];
    float prec1 = fminf(expf(-lv1), 1.0f);  // clip(exp(-lv1),0,1)
    double loss = *accum + (double)n * (double)lv0 + (double)prec1 * cost2 + (double)lv1;
    out[0] = (float)loss;
  }
}

extern "C" void kernel_launch(void* const* d_in, const int* in_sizes, int n_in,
                              void* d_out, int out_size, void* d_ws, size_t ws_size,
                              hipStream_t stream) {
  const float2* yt0 = (const float2*)d_in[0];
  const float*  yp0 = (const float*)d_in[2];
  const float*  yp1 = (const float*)d_in[3];
  const int*    Hj  = (const int*)d_in[4];
  const float*  lv  = (const float*)d_in[5];
  int n = in_sizes[0] / 2;  // y_true0 is [N,2]
  int m = in_sizes[4];
  int seParts = (n + SEBLK - 1) / SEBLK;   // 256 for n=262144 (k_main assumes <=256)

  // Replica count: 4 if workspace fits (~28 MB), else 1.
  int nrep = RMAX;
  {
    size_t need = (size_t)nrep * NBUCK * 4 * 2   // count, offArr
                + (size_t)NBUCK * 4 * 2          // countTot, sfxCnt
                + (size_t)NPART * 4
                + (size_t)n * 4 * 5              // seq, skey2 (8B), sidx, preS
                + 1024 * 4                        // blockTot
                + (size_t)m * 4 + 256;
    if (ws_size < need) nrep = 1;
  }
  int rmask = nrep - 1;

  char* ws = (char*)d_ws;
  size_t off = 0;
  unsigned* count  = (unsigned*)(ws + off); off += (size_t)nrep * NBUCK * 4;
  double*   accum  = (double*)(ws + off);   off += 16;
  size_t zbytes = off;  // everything above must start zeroed
  unsigned* offArr  = (unsigned*)(ws + off); off += (size_t)nrep * NBUCK * 4;
  unsigned* countTot= (unsigned*)(ws + off); off += (size_t)NBUCK * 4;
  unsigned* cntPart = (unsigned*)(ws + off); off += (size_t)NPART * 4;
  unsigned* sfxCnt  = (unsigned*)(ws + off); off += (size_t)NBUCK * 4;
  unsigned* seq     = (unsigned*)(ws + off); off += (size_t)n * 4;
  uint2*    skey2   = (uint2*)(ws + off);    off += (size_t)n * 8;   // 8-aligned
  unsigned* sidx    = (unsigned*)(ws + off); off += (size_t)n * 4;
  float*    preS    = (float*)(ws + off);    off += (size_t)n * 4;
  float*    blockTot= (float*)(ws + off);    off += 1024 * 4;
  float*    xh      = (float*)(ws + off);    off += (size_t)m * 4;

  hipMemsetAsync(d_ws, 0, zbytes, stream);

  int blk = 256;
  int g_n = (n + blk - 1) / blk;
  k_hist<<<g_n, blk, 0, stream>>>(yt0, n, rmask, count, seq);
  k_scan_reduce<<<NPART, SCAN_BLK, 0, stream>>>(count, nrep, countTot, offArr, cntPart);
  k_scan_final<<<NPART, SCAN_BLK, 0, stream>>>(countTot, cntPart, sfxCnt);
  k_scatter<<<g_n, blk, 0, stream>>>(yt0, yp0, n, rmask, countTot, sfxCnt, offArr, seq,
                                     skey2, sidx);
  k_scan_se<<<seParts, SEBLK, 0, stream>>>(skey2, n, preS, blockTot);
  k_main<<<g_n, blk, 0, stream>>>(yp1, Hj, n, m, seParts, countTot, sfxCnt,
                                  skey2, sidx, preS, blockTot, xh, accum);
  k_final<<<1, 1024, 0, stream>>>(xh, m, accum, lv, n, (float*)d_out);
}